// Round 3
// baseline (287.480 us; speedup 1.0000x reference)
//
#include <hip/hip_runtime.h>

// QRNN: SEQ=4096, BATCH=8, CIN=256, HID=256, K=2 (lookback=1)
// R5: fused scan via NORMAL launch + hand-rolled grid barrier (monotone atomic
//     counter, agent-scope fences). Residency guaranteed by __launch_bounds__(256,2):
//     >=2 blocks/CU schedulable -> 512 slots >= 512 blocks -> no deadlock.
//     Barrier counter zeroed by pack_kernel each launch.
//
// ws: zbf 16MB | fbf 16MB | Xbf 16MB (dead after gemm; Ac/Cc/Hs aliased) | Bm 0.5MB | bar 4B

#define SEQn 4096
#define NCH 2048          // BATCH*HID channels
#define CHUNK 32
#define NCHUNK 128
#define NBLK_SCAN 512

typedef __attribute__((ext_vector_type(8))) short bf16x8;
typedef __attribute__((ext_vector_type(4))) float floatx4;

__device__ __forceinline__ unsigned short f2bf(float x) {
  unsigned int u = __float_as_uint(x);
  u += 0x7fffu + ((u >> 16) & 1u);     // RNE
  return (unsigned short)(u >> 16);
}
__device__ __forceinline__ float bf2f(ushort u) {
  return __uint_as_float((unsigned int)u << 16);
}
__device__ __forceinline__ float bf2f_lo(unsigned int v) {   // low 16 bits
  return __uint_as_float(v << 16);
}
__device__ __forceinline__ float bf2f_hi(unsigned int v) {   // high 16 bits
  return __uint_as_float(v & 0xffff0000u);
}
__device__ __forceinline__ float sigf(float x) {
  return __builtin_amdgcn_rcpf(1.0f + __expf(-x));
}

// monotone grid barrier: each block adds 1; wait until counter >= target.
// Never reset within a launch -> no generation logic needed.
__device__ __forceinline__ void grid_bar(unsigned int* bar, unsigned int target) {
  __syncthreads();
  if (threadIdx.x == 0) {
    __threadfence();                                   // release (agent scope)
    __hip_atomic_fetch_add(bar, 1u, __ATOMIC_RELEASE, __HIP_MEMORY_SCOPE_AGENT);
    while (__hip_atomic_load(bar, __ATOMIC_ACQUIRE, __HIP_MEMORY_SCOPE_AGENT) < target) {
      __builtin_amdgcn_s_sleep(2);
    }
    __threadfence();                                   // acquire remote writes
  }
  __syncthreads();
}

// ---- 1) merged pack: blocks [0,1024) pack W, blocks [1024,9218) pack X ----
__global__ void pack_kernel(const float* __restrict__ X,
                            const float* __restrict__ Wz, const float* __restrict__ Wf,
                            ushort* __restrict__ Xbf, ushort* __restrict__ Bm,
                            unsigned int* __restrict__ bar) {
  if (blockIdx.x == 0 && threadIdx.x == 0)
    __hip_atomic_store(bar, 0u, __ATOMIC_RELAXED, __HIP_MEMORY_SCOPE_AGENT);
  if (blockIdx.x < 1024) {
    int idx = blockIdx.x * 256 + threadIdx.x;        // 0..262143
    int n = idx >> 9, kin = idx & 511;
    const float* W = (n < 256) ? Wz : Wf;
    int h = n & 255, c = kin & 255, tap = kin >> 8;  // kin<256: tap0 (X[s-1])
    Bm[idx] = f2bf(W[h * 512 + c * 2 + tap]);
  } else {
    int idx = (blockIdx.x - 1024) * 256 + threadIdx.x;
    const int total4 = ((SEQn + 1) * NCH) / 4;       // 2,097,664
    if (idx >= total4) return;
    const int pad4 = NCH / 4;
    float4 v;
    if (idx < pad4) { v.x = 0.f; v.y = 0.f; v.z = 0.f; v.w = 0.f; }
    else v = ((const float4*)X)[idx - pad4];
    ushort4 o;
    o.x = f2bf(v.x); o.y = f2bf(v.y); o.z = f2bf(v.z); o.w = f2bf(v.w);
    ((ushort4*)Xbf)[idx] = o;
  }
}

// ---- 2) GEMM 128x128, BK=64, mfma_f32_16x16x32_bf16, swizzled LDS ----
// LDS seg (row, s) holds global k-seg s^(row&7)  (seg = 16B = 8 bf16)
__global__ __launch_bounds__(256) void gemm_kernel(
    const ushort* __restrict__ Xbf, const ushort* __restrict__ Bm,
    const float* __restrict__ bz, const float* __restrict__ bfb,
    ushort* __restrict__ zout, ushort* __restrict__ fout) {
  __shared__ __align__(16) char smem_raw[32768];
  ushort* sA = (ushort*)smem_raw;                 // 128 rows x 64 k
  ushort* sB = (ushort*)(smem_raw + 16384);       // 128 cols x 64 k
  ushort* sT = (ushort*)smem_raw;                 // epilogue 64 x 136

  const int tid  = threadIdx.x;
  const int wave = tid >> 6;
  const int lane = tid & 63;
  const int quad = lane >> 4;
  const int lrow = lane & 15;
  const int wm = wave >> 1;          // 2x2 wave grid, 64x64 each
  const int wn = wave & 1;
  const int bm = blockIdx.x;         // 0..255
  const int bn = blockIdx.y;         // 0..3 (0,1=Z; 2,3=F)

  floatx4 acc[4][4];
#pragma unroll
  for (int i = 0; i < 4; ++i)
#pragma unroll
    for (int j = 0; j < 4; ++j)
      acc[i][j] = (floatx4){0.f, 0.f, 0.f, 0.f};

  // staging coords: 4 segs each for A and B per thread
  int rowS[4], gko[4];               // LDS row, global k-seg offset (elements)
#pragma unroll
  for (int it = 0; it < 4; ++it) {
    int g = wave * 256 + it * 64 + lane;     // LDS seg index 0..1023
    int row = g >> 3, ks8 = g & 7;
    rowS[it] = row;
    gko[it] = (ks8 ^ (row & 7)) * 8;         // swizzled global k offset
  }
  char* ldsA = (char*)sA + wave * 4096 + (lane << 4);
  char* ldsB = (char*)sB + wave * 4096 + (lane << 4);

  for (int k0 = 0; k0 < 512; k0 += 64) {
    __syncthreads();                 // prev iter ds_reads done
#pragma unroll
    for (int it = 0; it < 4; ++it) {
      const int kk = k0 + gko[it];
      const int cA = (kk < 256) ? kk : kk + 1792;     // tap1 lives +2048-256
      __builtin_amdgcn_global_load_lds(
          (const __attribute__((address_space(1))) void*)(Xbf + (size_t)(bm * 128 + rowS[it]) * 256 + cA),
          (__attribute__((address_space(3))) void*)(ldsA + it * 1024), 16, 0, 0);
      __builtin_amdgcn_global_load_lds(
          (const __attribute__((address_space(1))) void*)(Bm + (size_t)(bn * 128 + rowS[it]) * 512 + kk),
          (__attribute__((address_space(3))) void*)(ldsB + it * 1024), 16, 0, 0);
    }
    __syncthreads();

    bf16x8 af[4][2], bfr[4][2];
#pragma unroll
    for (int fi = 0; fi < 4; ++fi) {
      const int r = wm * 64 + fi * 16 + lrow;
#pragma unroll
      for (int ks = 0; ks < 2; ++ks) {
        const int s = (ks * 4 + quad) ^ (r & 7);
        af[fi][ks] = *(const bf16x8*)&sA[r * 64 + s * 8];
      }
    }
#pragma unroll
    for (int fj = 0; fj < 4; ++fj) {
      const int r = wn * 64 + fj * 16 + lrow;
#pragma unroll
      for (int ks = 0; ks < 2; ++ks) {
        const int s = (ks * 4 + quad) ^ (r & 7);
        bfr[fj][ks] = *(const bf16x8*)&sB[r * 64 + s * 8];
      }
    }
#pragma unroll
    for (int ks = 0; ks < 2; ++ks)
#pragma unroll
      for (int fi = 0; fi < 4; ++fi)
#pragma unroll
        for (int fj = 0; fj < 4; ++fj)
          acc[fi][fj] = __builtin_amdgcn_mfma_f32_16x16x32_bf16(af[fi][ks], bfr[fj][ks], acc[fi][fj], 0, 0, 0);
  }

  // epilogue: activation -> bf16 -> sT (64 x 136 padded) -> coalesced dwordx4
  const bool isZ = (bn < 2);
  ushort* gout = isZ ? zout : fout;
  const int ncol0 = (bn & 1) * 128;
  const float* bias = isZ ? bz : bfb;
  float bv[4];
#pragma unroll
  for (int fj = 0; fj < 4; ++fj)
    bv[fj] = bias[ncol0 + wn * 64 + fj * 16 + lrow];

  for (int round = 0; round < 2; ++round) {
    __syncthreads();
    if (wm == round) {
#pragma unroll
      for (int fi = 0; fi < 4; ++fi)
#pragma unroll
        for (int fj = 0; fj < 4; ++fj)
#pragma unroll
          for (int r = 0; r < 4; ++r) {
            float v = acc[fi][fj][r] + bv[fj];
            float o = isZ ? (v * sigf(1.702f * v)) : sigf(v);
            sT[(fi * 16 + quad * 4 + r) * 136 + wn * 64 + fj * 16 + lrow] = f2bf(o);
          }
    }
    __syncthreads();
#pragma unroll
    for (int it = 0; it < 4; ++it) {
      int e = tid + it * 256;           // 1024 segs = 64 rows x 16 segs
      int row = e >> 4, seg = e & 15;
      uint4 v = *(uint4*)&sT[row * 136 + seg * 8];
      *(uint4*)(gout + (size_t)(bm * 128 + round * 64 + row) * 256 + ncol0 + seg * 8) = v;
    }
  }
}

// ---- 3) fused scan: phase A (chunk reduce, z/f -> regs) | grid_bar |
//         phase B (cross-chunk Hillis-Steele) | grid_bar | phase C (replay from regs)
// grid = 512 blocks x 256 threads = 131072 = 128 chunks x 1024 ch-pairs  (phases A/C)
//                                          = 2048 channels x 64 lanes     (phase B)
__global__ __launch_bounds__(256, 2) void scan_fused(
    const float* __restrict__ hidden,
    const ushort* __restrict__ z, const ushort* __restrict__ f,
    float* __restrict__ Ac, float* __restrict__ Cc, float* __restrict__ Hs,
    float* __restrict__ out, unsigned int* __restrict__ bar) {
  const int t = blockIdx.x * 256 + threadIdx.x;    // 0..131071
  const int ch2 = t & 1023;                        // channel-pair
  const int j = t >> 10;                           // chunk 0..127
  const size_t base = (size_t)j * CHUNK * NCH + 2 * ch2;

  // ---- phase A: load chunk once, keep packed in registers ----
  unsigned int zreg[CHUNK], freg[CHUNK];
  float A0 = 1.0f, C0 = 0.0f, A1 = 1.0f, C1 = 0.0f;
#pragma unroll
  for (int i = 0; i < CHUNK; ++i) {
    unsigned int fv = *(const unsigned int*)(f + base + (size_t)i * NCH);
    unsigned int zv = *(const unsigned int*)(z + base + (size_t)i * NCH);
    freg[i] = fv; zreg[i] = zv;
    float f0 = bf2f_lo(fv), f1 = bf2f_hi(fv);
    float a0 = 1.0f - f0, a1 = 1.0f - f1;
    C0 = fmaf(a0, C0, f0 * bf2f_lo(zv)); A0 *= a0;
    C1 = fmaf(a1, C1, f1 * bf2f_hi(zv)); A1 *= a1;
  }
  {
    float2 Av = {A0, A1}, Cv = {C0, C1};
    *(float2*)(Ac + (size_t)j * NCH + 2 * ch2) = Av;
    *(float2*)(Cc + (size_t)j * NCH + 2 * ch2) = Cv;
  }

  grid_bar(bar, NBLK_SCAN);

  // ---- phase B: cross-chunk scan, one wave per channel ----
  {
    const int lane = threadIdx.x & 63;
    const int ch = blockIdx.x * 4 + (threadIdx.x >> 6);
    const int j0 = 2 * lane, j1 = 2 * lane + 1;
    float a0 = Ac[j0 * NCH + ch], c0 = Cc[j0 * NCH + ch];
    float a1 = Ac[j1 * NCH + ch], c1 = Cc[j1 * NCH + ch];
    float a = a0 * a1;
    float c = fmaf(a1, c0, c1);
#pragma unroll
    for (int d = 1; d < 64; d <<= 1) {
      float pa = __shfl_up(a, d, 64);
      float pc = __shfl_up(c, d, 64);
      if (lane >= d) { c = fmaf(a, pc, c); a *= pa; }
    }
    float xa = __shfl_up(a, 1, 64), xc = __shfl_up(c, 1, 64);
    if (lane == 0) { xa = 1.0f; xc = 0.0f; }
    float h0 = hidden[ch];
    float hs0 = fmaf(xa, h0, xc);
    Hs[j0 * NCH + ch] = hs0;
    Hs[j1 * NCH + ch] = fmaf(a0, hs0, c0);
  }

  grid_bar(bar, 2 * NBLK_SCAN);

  // ---- phase C: replay within chunk from registers ----
  {
    float2 hv = *(const float2*)(Hs + (size_t)j * NCH + 2 * ch2);
    float h0 = hv.x, h1 = hv.y;
    float* op = out + base;
#pragma unroll
    for (int i = 0; i < CHUNK; ++i) {
      unsigned int fv = freg[i], zv = zreg[i];
      float f0 = bf2f_lo(fv), f1 = bf2f_hi(fv);
      h0 = fmaf(f0, bf2f_lo(zv) - h0, h0);
      h1 = fmaf(f1, bf2f_hi(zv) - h1, h1);
      float2 o = {h0, h1};
      *(float2*)(op + (size_t)i * NCH) = o;
    }
    if (j == NCHUNK - 1) {
      float2 o = {h0, h1};
      *(float2*)(out + (size_t)SEQn * NCH + 2 * ch2) = o;   // h_last row
    }
  }
}

extern "C" void kernel_launch(void* const* d_in, const int* in_sizes, int n_in,
                              void* d_out, int out_size, void* d_ws, size_t ws_size,
                              hipStream_t stream) {
  const float* X      = (const float*)d_in[0];
  const float* hidden = (const float*)d_in[1];
  const float* Wz     = (const float*)d_in[2];
  const float* bz     = (const float*)d_in[3];
  const float* Wf     = (const float*)d_in[4];
  const float* bfb    = (const float*)d_in[5];
  float* out = (float*)d_out;

  char* ws = (char*)d_ws;
  ushort* zbf = (ushort*)ws;                       // 16,777,216 B
  ushort* fbf = (ushort*)(ws + 16777216);          // 16,777,216 B
  ushort* Xbf = (ushort*)(ws + 33554432);          // 16,781,312 B (dead after gemm)
  ushort* Bm  = (ushort*)(ws + 50335744);          //    524,288 B
  unsigned int* bar = (unsigned int*)(ws + 50860032);  // 4 B, zeroed by pack
  // aliased over Xbf (used only after gemm completes):
  float* Ac = (float*)(ws + 33554432);
  float* Cc = (float*)(ws + 34603008);
  float* Hs = (float*)(ws + 35651584);

  pack_kernel<<<9218, 256, 0, stream>>>(X, Wz, Wf, Xbf, Bm, bar);
  dim3 ggrid(256, 4);
  gemm_kernel<<<ggrid, 256, 0, stream>>>(Xbf, Bm, bz, bfb, zbf, fbf);
  scan_fused<<<512, 256, 0, stream>>>(hidden, zbf, fbf, Ac, Cc, Hs, out, bar);
}

// Round 4
// 153.794 us; speedup vs baseline: 1.8693x; 1.8693x over previous
//
#include <hip/hip_runtime.h>

// QRNN: SEQ=4096, BATCH=8, CIN=256, HID=256, K=2 (lookback=1)
// R6: R3 structure (5 kernels, verified) + GEMM double-buffered K-loop:
//     prefetch next tile via global_load_lds into alternate 32KB LDS buffer
//     while computing current; ONE __syncthreads per K-step (drain overlaps MFMA).
//     LDS 64KB -> still 2 blocks/CU. Grid-sync fusion abandoned (R5: barrier melt).
//
// ws: zbf 16MB | fbf 16MB | Xbf 16MB (dead after gemm; Ac/Cc/Hs aliased) | Bm 0.5MB

#define SEQn 4096
#define NCH 2048          // BATCH*HID channels
#define CHUNK 32
#define NCHUNK 128

typedef __attribute__((ext_vector_type(8))) short bf16x8;
typedef __attribute__((ext_vector_type(4))) float floatx4;

__device__ __forceinline__ unsigned short f2bf(float x) {
  unsigned int u = __float_as_uint(x);
  u += 0x7fffu + ((u >> 16) & 1u);     // RNE
  return (unsigned short)(u >> 16);
}
__device__ __forceinline__ float bf2f(ushort u) {
  return __uint_as_float((unsigned int)u << 16);
}
__device__ __forceinline__ float sigf(float x) {
  return __builtin_amdgcn_rcpf(1.0f + __expf(-x));
}

// ---- 1) merged pack: blocks [0,1024) pack W, blocks [1024,9218) pack X ----
__global__ void pack_kernel(const float* __restrict__ X,
                            const float* __restrict__ Wz, const float* __restrict__ Wf,
                            ushort* __restrict__ Xbf, ushort* __restrict__ Bm) {
  if (blockIdx.x < 1024) {
    int idx = blockIdx.x * 256 + threadIdx.x;        // 0..262143
    int n = idx >> 9, kin = idx & 511;
    const float* W = (n < 256) ? Wz : Wf;
    int h = n & 255, c = kin & 255, tap = kin >> 8;  // kin<256: tap0 (X[s-1])
    Bm[idx] = f2bf(W[h * 512 + c * 2 + tap]);
  } else {
    int idx = (blockIdx.x - 1024) * 256 + threadIdx.x;
    const int total4 = ((SEQn + 1) * NCH) / 4;       // 2,097,664
    if (idx >= total4) return;
    const int pad4 = NCH / 4;
    float4 v;
    if (idx < pad4) { v.x = 0.f; v.y = 0.f; v.z = 0.f; v.w = 0.f; }
    else v = ((const float4*)X)[idx - pad4];
    ushort4 o;
    o.x = f2bf(v.x); o.y = f2bf(v.y); o.z = f2bf(v.z); o.w = f2bf(v.w);
    ((ushort4*)Xbf)[idx] = o;
  }
}

// ---- 2) GEMM 128x128, BK=64, mfma_f32_16x16x32_bf16, swizzled LDS, dbuf ----
// LDS seg (row, s) holds global k-seg s^(row&7)  (seg = 16B = 8 bf16)
__global__ __launch_bounds__(256) void gemm_kernel(
    const ushort* __restrict__ Xbf, const ushort* __restrict__ Bm,
    const float* __restrict__ bz, const float* __restrict__ bfb,
    ushort* __restrict__ zout, ushort* __restrict__ fout) {
  __shared__ __align__(16) char smem_raw[65536];
  // buffer c: sA at c*32768, sB at c*32768+16384 (each 128 rows x 64 k bf16)
  ushort* sT = (ushort*)smem_raw;                 // epilogue 64 x 136 (17.4KB)

  const int tid  = threadIdx.x;
  const int wave = tid >> 6;
  const int lane = tid & 63;
  const int quad = lane >> 4;
  const int lrow = lane & 15;
  const int wm = wave >> 1;          // 2x2 wave grid, 64x64 each
  const int wn = wave & 1;
  const int bm = blockIdx.x;         // 0..255
  const int bn = blockIdx.y;         // 0..3 (0,1=Z; 2,3=F)

  floatx4 acc[4][4];
#pragma unroll
  for (int i = 0; i < 4; ++i)
#pragma unroll
    for (int j = 0; j < 4; ++j)
      acc[i][j] = (floatx4){0.f, 0.f, 0.f, 0.f};

  // staging coords: 4 segs each for A and B per thread
  int rowS[4], gko[4];               // LDS row, global k-seg offset (elements)
#pragma unroll
  for (int it = 0; it < 4; ++it) {
    int g = wave * 256 + it * 64 + lane;     // LDS seg index 0..1023
    int row = g >> 3, ks8 = g & 7;
    rowS[it] = row;
    gko[it] = (ks8 ^ (row & 7)) * 8;         // swizzled global k offset
  }

  const ushort* Arow = Xbf + (size_t)(bm * 128) * 256;
  const ushort* Brow = Bm + (size_t)(bn * 128) * 512;

  // stage tile (k0) into buffer cur
#define STAGE(curb, k0)                                                          \
  {                                                                              \
    char* lA = smem_raw + (curb) * 32768 + wave * 4096 + (lane << 4);            \
    char* lB = lA + 16384;                                                       \
    _Pragma("unroll")                                                            \
    for (int it = 0; it < 4; ++it) {                                             \
      const int kk = (k0) + gko[it];                                             \
      const int cA = (kk < 256) ? kk : kk + 1792;  /* tap1 lives +2048-256 */    \
      __builtin_amdgcn_global_load_lds(                                          \
          (const __attribute__((address_space(1))) void*)(Arow + (size_t)rowS[it] * 256 + cA), \
          (__attribute__((address_space(3))) void*)(lA + it * 1024), 16, 0, 0);  \
      __builtin_amdgcn_global_load_lds(                                          \
          (const __attribute__((address_space(1))) void*)(Brow + (size_t)rowS[it] * 512 + kk), \
          (__attribute__((address_space(3))) void*)(lB + it * 1024), 16, 0, 0);  \
    }                                                                            \
  }

  STAGE(0, 0);
  __syncthreads();                   // implicit vmcnt(0) drain: tile0 ready

  int cur = 0;
  for (int t = 0; t < 8; ++t) {
    if (t < 7) STAGE(cur ^ 1, (t + 1) * 64);   // prefetch next tile (in flight during MFMA)

    const ushort* sA = (const ushort*)(smem_raw + cur * 32768);
    const ushort* sB = sA + 8192;              // +16384 bytes

    bf16x8 af[4][2], bfr[4][2];
#pragma unroll
    for (int fi = 0; fi < 4; ++fi) {
      const int r = wm * 64 + fi * 16 + lrow;
#pragma unroll
      for (int ks = 0; ks < 2; ++ks) {
        const int s = (ks * 4 + quad) ^ (r & 7);
        af[fi][ks] = *(const bf16x8*)&sA[r * 64 + s * 8];
      }
    }
#pragma unroll
    for (int fj = 0; fj < 4; ++fj) {
      const int r = wn * 64 + fj * 16 + lrow;
#pragma unroll
      for (int ks = 0; ks < 2; ++ks) {
        const int s = (ks * 4 + quad) ^ (r & 7);
        bfr[fj][ks] = *(const bf16x8*)&sB[r * 64 + s * 8];
      }
    }
#pragma unroll
    for (int ks = 0; ks < 2; ++ks)
#pragma unroll
      for (int fi = 0; fi < 4; ++fi)
#pragma unroll
        for (int fj = 0; fj < 4; ++fj)
          acc[fi][fj] = __builtin_amdgcn_mfma_f32_16x16x32_bf16(af[fi][ks], bfr[fj][ks], acc[fi][fj], 0, 0, 0);

    __syncthreads();                 // drains prefetch (vmcnt 0) + barrier
    cur ^= 1;
  }
#undef STAGE

  // epilogue: activation -> bf16 -> sT (64 x 136 padded) -> coalesced dwordx4
  const bool isZ = (bn < 2);
  ushort* gout = isZ ? zout : fout;
  const int ncol0 = (bn & 1) * 128;
  const float* bias = isZ ? bz : bfb;
  float bv[4];
#pragma unroll
  for (int fj = 0; fj < 4; ++fj)
    bv[fj] = bias[ncol0 + wn * 64 + fj * 16 + lrow];

  for (int round = 0; round < 2; ++round) {
    __syncthreads();
    if (wm == round) {
#pragma unroll
      for (int fi = 0; fi < 4; ++fi)
#pragma unroll
        for (int fj = 0; fj < 4; ++fj)
#pragma unroll
          for (int r = 0; r < 4; ++r) {
            float v = acc[fi][fj][r] + bv[fj];
            float o = isZ ? (v * sigf(1.702f * v)) : sigf(v);
            sT[(fi * 16 + quad * 4 + r) * 136 + wn * 64 + fj * 16 + lrow] = f2bf(o);
          }
    }
    __syncthreads();
#pragma unroll
    for (int it = 0; it < 4; ++it) {
      int e = tid + it * 256;           // 1024 segs = 64 rows x 16 segs
      int row = e >> 4, seg = e & 15;
      uint4 v = *(uint4*)&sT[row * 136 + seg * 8];
      *(uint4*)(gout + (size_t)(bm * 128 + round * 64 + row) * 256 + ncol0 + seg * 8) = v;
    }
  }
}

// ---- 3) per-chunk reduction, 2 channels/thread ----
__global__ void scanA_kernel(const ushort* __restrict__ z, const ushort* __restrict__ f,
                             float* __restrict__ Ac, float* __restrict__ Cc) {
  int t = blockIdx.x * blockDim.x + threadIdx.x;   // 0..131071
  int ch2 = t & 1023;
  int j = t >> 10;                                  // 0..127
  const size_t base = (size_t)j * CHUNK * NCH + 2 * ch2;
  const ushort* zp = z + base;
  const ushort* fp = f + base;
  float A0 = 1.0f, C0 = 0.0f, A1 = 1.0f, C1 = 0.0f;
#pragma unroll
  for (int i = 0; i < CHUNK; ++i) {
    ushort2 fv = *(const ushort2*)(fp + (size_t)i * NCH);
    ushort2 zv = *(const ushort2*)(zp + (size_t)i * NCH);
    float f0 = bf2f(fv.x), f1 = bf2f(fv.y);
    float a0 = 1.0f - f0, a1 = 1.0f - f1;
    C0 = fmaf(a0, C0, f0 * bf2f(zv.x)); A0 *= a0;
    C1 = fmaf(a1, C1, f1 * bf2f(zv.y)); A1 *= a1;
  }
  float2 Av = {A0, A1}, Cv = {C0, C1};
  *(float2*)(Ac + (size_t)j * NCH + 2 * ch2) = Av;
  *(float2*)(Cc + (size_t)j * NCH + 2 * ch2) = Cv;
}

// ---- 4) cross-chunk scan: one wave per channel, shfl Hillis-Steele ----
__global__ void scanB_kernel(const float* __restrict__ hidden,
                             const float* __restrict__ Ac, const float* __restrict__ Cc,
                             float* __restrict__ Hs) {
  const int lane = threadIdx.x & 63;
  const int ch = blockIdx.x * 4 + (threadIdx.x >> 6);   // 512 blocks x 4 waves
  const int j0 = 2 * lane, j1 = 2 * lane + 1;
  float a0 = Ac[j0 * NCH + ch], c0 = Cc[j0 * NCH + ch];
  float a1 = Ac[j1 * NCH + ch], c1 = Cc[j1 * NCH + ch];
  float a = a0 * a1;
  float c = fmaf(a1, c0, c1);
#pragma unroll
  for (int d = 1; d < 64; d <<= 1) {
    float pa = __shfl_up(a, d, 64);
    float pc = __shfl_up(c, d, 64);
    if (lane >= d) { c = fmaf(a, pc, c); a *= pa; }
  }
  float xa = __shfl_up(a, 1, 64), xc = __shfl_up(c, 1, 64);
  if (lane == 0) { xa = 1.0f; xc = 0.0f; }
  float h0 = hidden[ch];
  float hs0 = fmaf(xa, h0, xc);
  Hs[j0 * NCH + ch] = hs0;
  Hs[j1 * NCH + ch] = fmaf(a0, hs0, c0);
}

// ---- 5) replay within chunk, 2 channels/thread, fp32 out ----
__global__ void scanC_kernel(const ushort* __restrict__ z, const ushort* __restrict__ f,
                             const float* __restrict__ Hs, float* __restrict__ out) {
  int t = blockIdx.x * blockDim.x + threadIdx.x;   // 0..131071
  int ch2 = t & 1023;
  int j = t >> 10;
  float2 hv = *(const float2*)(Hs + (size_t)j * NCH + 2 * ch2);
  float h0 = hv.x, h1 = hv.y;
  const size_t base = (size_t)j * CHUNK * NCH + 2 * ch2;
  const ushort* zp = z + base;
  const ushort* fp = f + base;
  float* op = out + base;
#pragma unroll
  for (int i = 0; i < CHUNK; ++i) {
    ushort2 fv = *(const ushort2*)(fp + (size_t)i * NCH);
    ushort2 zv = *(const ushort2*)(zp + (size_t)i * NCH);
    float f0 = bf2f(fv.x), f1 = bf2f(fv.y);
    h0 = fmaf(f0, bf2f(zv.x) - h0, h0);
    h1 = fmaf(f1, bf2f(zv.y) - h1, h1);
    float2 o = {h0, h1};
    *(float2*)(op + (size_t)i * NCH) = o;
  }
  if (j == NCHUNK - 1) {
    float2 o = {h0, h1};
    *(float2*)(out + (size_t)SEQn * NCH + 2 * ch2) = o;   // h_last row
  }
}

extern "C" void kernel_launch(void* const* d_in, const int* in_sizes, int n_in,
                              void* d_out, int out_size, void* d_ws, size_t ws_size,
                              hipStream_t stream) {
  const float* X      = (const float*)d_in[0];
  const float* hidden = (const float*)d_in[1];
  const float* Wz     = (const float*)d_in[2];
  const float* bz     = (const float*)d_in[3];
  const float* Wf     = (const float*)d_in[4];
  const float* bfb    = (const float*)d_in[5];
  float* out = (float*)d_out;

  char* ws = (char*)d_ws;
  ushort* zbf = (ushort*)ws;                       // 16,777,216 B
  ushort* fbf = (ushort*)(ws + 16777216);          // 16,777,216 B
  ushort* Xbf = (ushort*)(ws + 33554432);          // 16,781,312 B (dead after gemm)
  ushort* Bm  = (ushort*)(ws + 50335744);          //    524,288 B
  // aliased over Xbf (used only after gemm completes):
  float* Ac = (float*)(ws + 33554432);
  float* Cc = (float*)(ws + 34603008);
  float* Hs = (float*)(ws + 35651584);

  pack_kernel<<<9218, 256, 0, stream>>>(X, Wz, Wf, Xbf, Bm);
  dim3 ggrid(256, 4);
  gemm_kernel<<<ggrid, 256, 0, stream>>>(Xbf, Bm, bz, bfb, zbf, fbf);
  scanA_kernel<<<512, 256, 0, stream>>>(zbf, fbf, Ac, Cc);
  scanB_kernel<<<512, 256, 0, stream>>>(hidden, Ac, Cc, Hs);
  scanC_kernel<<<512, 256, 0, stream>>>(zbf, fbf, Hs, out);
}

// Round 5
// 139.500 us; speedup vs baseline: 2.0608x; 1.1025x over previous
//
#include <hip/hip_runtime.h>

// QRNN: SEQ=4096, BATCH=8, CIN=256, HID=256, K=2 (lookback=1)
// R7: latency-bound gemm fix: tile 128x128 -> 64x128 (grid 512x4, 2x blocks),
//     acc/wave halved -> ~100 VGPR -> 5 waves/SIMD; LDS 24KB single-buffer ->
//     ~5 blocks/CU resident (vs 2). R3's verified 2-barrier K-step. Dbuf reverted
//     (R6: -9.4us regression, LDS-capped occupancy). Scans = verified R3 A/B/C.
//
// ws: zbf 16MB | fbf 16MB | Xbf 16MB (dead after gemm; Ac/Cc/Hs aliased) | Bm 0.5MB

#define SEQn 4096
#define NCH 2048          // BATCH*HID channels
#define CHUNK 32
#define NCHUNK 128

typedef __attribute__((ext_vector_type(8))) short bf16x8;
typedef __attribute__((ext_vector_type(4))) float floatx4;

__device__ __forceinline__ unsigned short f2bf(float x) {
  unsigned int u = __float_as_uint(x);
  u += 0x7fffu + ((u >> 16) & 1u);     // RNE
  return (unsigned short)(u >> 16);
}
__device__ __forceinline__ float bf2f(ushort u) {
  return __uint_as_float((unsigned int)u << 16);
}
__device__ __forceinline__ float sigf(float x) {
  return __builtin_amdgcn_rcpf(1.0f + __expf(-x));
}

// ---- 1) merged pack: blocks [0,1024) pack W, blocks [1024,9218) pack X ----
__global__ void pack_kernel(const float* __restrict__ X,
                            const float* __restrict__ Wz, const float* __restrict__ Wf,
                            ushort* __restrict__ Xbf, ushort* __restrict__ Bm) {
  if (blockIdx.x < 1024) {
    int idx = blockIdx.x * 256 + threadIdx.x;        // 0..262143
    int n = idx >> 9, kin = idx & 511;
    const float* W = (n < 256) ? Wz : Wf;
    int h = n & 255, c = kin & 255, tap = kin >> 8;  // kin<256: tap0 (X[s-1])
    Bm[idx] = f2bf(W[h * 512 + c * 2 + tap]);
  } else {
    int idx = (blockIdx.x - 1024) * 256 + threadIdx.x;
    const int total4 = ((SEQn + 1) * NCH) / 4;       // 2,097,664
    if (idx >= total4) return;
    const int pad4 = NCH / 4;
    float4 v;
    if (idx < pad4) { v.x = 0.f; v.y = 0.f; v.z = 0.f; v.w = 0.f; }
    else v = ((const float4*)X)[idx - pad4];
    ushort4 o;
    o.x = f2bf(v.x); o.y = f2bf(v.y); o.z = f2bf(v.z); o.w = f2bf(v.w);
    ((ushort4*)Xbf)[idx] = o;
  }
}

// ---- 2) GEMM 64x128, BK=64, mfma_f32_16x16x32_bf16, swizzled LDS ----
// LDS seg (row, s) holds global k-seg s^(row&7)  (seg = 16B = 8 bf16)
__global__ __launch_bounds__(256) void gemm_kernel(
    const ushort* __restrict__ Xbf, const ushort* __restrict__ Bm,
    const float* __restrict__ bz, const float* __restrict__ bfb,
    ushort* __restrict__ zout, ushort* __restrict__ fout) {
  __shared__ __align__(16) char smem_raw[24576];
  ushort* sA = (ushort*)smem_raw;                 // 64 rows x 64 k   (8KB)
  ushort* sB = sA + 4096;                         // 128 cols x 64 k  (16KB)
  ushort* sT = (ushort*)smem_raw;                 // epilogue 64 x 136 (17.4KB)

  const int tid  = threadIdx.x;
  const int wave = tid >> 6;
  const int lane = tid & 63;
  const int quad = lane >> 4;
  const int lrow = lane & 15;
  const int wm = wave >> 1;          // 2x2 wave grid, each 32x64 output
  const int wn = wave & 1;
  const int bm = blockIdx.x;         // 0..511
  const int bn = blockIdx.y;         // 0..3 (0,1=Z; 2,3=F)

  floatx4 acc[2][4];
#pragma unroll
  for (int i = 0; i < 2; ++i)
#pragma unroll
    for (int j = 0; j < 4; ++j)
      acc[i][j] = (floatx4){0.f, 0.f, 0.f, 0.f};

  // staging coords: A 2 segs/thread (512 segs), B 4 segs/thread (1024 segs)
  int rowA[2], gkoA[2], rowB[4], gkoB[4];
#pragma unroll
  for (int it = 0; it < 2; ++it) {
    int g = it * 256 + wave * 64 + lane;     // 0..511
    int row = g >> 3, s = g & 7;
    rowA[it] = row;                          // 0..63
    gkoA[it] = (s ^ (row & 7)) * 8;
  }
#pragma unroll
  for (int it = 0; it < 4; ++it) {
    int g = it * 256 + wave * 64 + lane;     // 0..1023
    int row = g >> 3, s = g & 7;
    rowB[it] = row;                          // 0..127
    gkoB[it] = (s ^ (row & 7)) * 8;
  }
  char* ldsA = smem_raw + wave * 1024 + (lane << 4);
  char* ldsB = smem_raw + 8192 + wave * 1024 + (lane << 4);

  const ushort* Arow = Xbf + (size_t)(bm * 64) * 256;
  const ushort* Brow = Bm + (size_t)(bn * 128) * 512;

  for (int k0 = 0; k0 < 512; k0 += 64) {
    __syncthreads();                 // prev iter ds_reads done
#pragma unroll
    for (int it = 0; it < 2; ++it) {
      const int kk = k0 + gkoA[it];
      const int cA = (kk < 256) ? kk : kk + 1792;     // tap1 lives +2048-256
      __builtin_amdgcn_global_load_lds(
          (const __attribute__((address_space(1))) void*)(Arow + (size_t)rowA[it] * 256 + cA),
          (__attribute__((address_space(3))) void*)(ldsA + it * 4096), 16, 0, 0);
    }
#pragma unroll
    for (int it = 0; it < 4; ++it) {
      const int kk = k0 + gkoB[it];
      __builtin_amdgcn_global_load_lds(
          (const __attribute__((address_space(1))) void*)(Brow + (size_t)rowB[it] * 512 + kk),
          (__attribute__((address_space(3))) void*)(ldsB + it * 4096), 16, 0, 0);
    }
    __syncthreads();

    bf16x8 af[2][2], bfr[4][2];
#pragma unroll
    for (int fi = 0; fi < 2; ++fi) {
      const int r = wm * 32 + fi * 16 + lrow;
#pragma unroll
      for (int ks = 0; ks < 2; ++ks) {
        const int s = (ks * 4 + quad) ^ (r & 7);
        af[fi][ks] = *(const bf16x8*)&sA[r * 64 + s * 8];
      }
    }
#pragma unroll
    for (int fj = 0; fj < 4; ++fj) {
      const int r = wn * 64 + fj * 16 + lrow;
#pragma unroll
      for (int ks = 0; ks < 2; ++ks) {
        const int s = (ks * 4 + quad) ^ (r & 7);
        bfr[fj][ks] = *(const bf16x8*)&sB[r * 64 + s * 8];
      }
    }
#pragma unroll
    for (int ks = 0; ks < 2; ++ks)
#pragma unroll
      for (int fi = 0; fi < 2; ++fi)
#pragma unroll
        for (int fj = 0; fj < 4; ++fj)
          acc[fi][fj] = __builtin_amdgcn_mfma_f32_16x16x32_bf16(af[fi][ks], bfr[fj][ks], acc[fi][fj], 0, 0, 0);
  }

  // epilogue: activation -> bf16 -> sT (64 x 136 padded) -> coalesced dwordx4
  const bool isZ = (bn < 2);
  ushort* gout = isZ ? zout : fout;
  const int ncol0 = (bn & 1) * 128;
  const float* bias = isZ ? bz : bfb;
  float bv[4];
#pragma unroll
  for (int fj = 0; fj < 4; ++fj)
    bv[fj] = bias[ncol0 + wn * 64 + fj * 16 + lrow];

  __syncthreads();                   // all ds_reads of sA/sB done (sT aliases)
#pragma unroll
  for (int fi = 0; fi < 2; ++fi)
#pragma unroll
    for (int fj = 0; fj < 4; ++fj)
#pragma unroll
      for (int r = 0; r < 4; ++r) {
        float v = acc[fi][fj][r] + bv[fj];
        float o = isZ ? (v * sigf(1.702f * v)) : sigf(v);
        sT[(wm * 32 + fi * 16 + quad * 4 + r) * 136 + wn * 64 + fj * 16 + lrow] = f2bf(o);
      }
  __syncthreads();
#pragma unroll
  for (int it = 0; it < 4; ++it) {
    int e = tid + it * 256;           // 1024 segs = 64 rows x 16 segs
    int row = e >> 4, seg = e & 15;
    uint4 v = *(uint4*)&sT[row * 136 + seg * 8];
    *(uint4*)(gout + (size_t)(bm * 64 + row) * 256 + ncol0 + seg * 8) = v;
  }
}

// ---- 3) per-chunk reduction, 2 channels/thread ----
__global__ void scanA_kernel(const ushort* __restrict__ z, const ushort* __restrict__ f,
                             float* __restrict__ Ac, float* __restrict__ Cc) {
  int t = blockIdx.x * blockDim.x + threadIdx.x;   // 0..131071
  int ch2 = t & 1023;
  int j = t >> 10;                                  // 0..127
  const size_t base = (size_t)j * CHUNK * NCH + 2 * ch2;
  const ushort* zp = z + base;
  const ushort* fp = f + base;
  float A0 = 1.0f, C0 = 0.0f, A1 = 1.0f, C1 = 0.0f;
#pragma unroll
  for (int i = 0; i < CHUNK; ++i) {
    ushort2 fv = *(const ushort2*)(fp + (size_t)i * NCH);
    ushort2 zv = *(const ushort2*)(zp + (size_t)i * NCH);
    float f0 = bf2f(fv.x), f1 = bf2f(fv.y);
    float a0 = 1.0f - f0, a1 = 1.0f - f1;
    C0 = fmaf(a0, C0, f0 * bf2f(zv.x)); A0 *= a0;
    C1 = fmaf(a1, C1, f1 * bf2f(zv.y)); A1 *= a1;
  }
  float2 Av = {A0, A1}, Cv = {C0, C1};
  *(float2*)(Ac + (size_t)j * NCH + 2 * ch2) = Av;
  *(float2*)(Cc + (size_t)j * NCH + 2 * ch2) = Cv;
}

// ---- 4) cross-chunk scan: one wave per channel, shfl Hillis-Steele ----
__global__ void scanB_kernel(const float* __restrict__ hidden,
                             const float* __restrict__ Ac, const float* __restrict__ Cc,
                             float* __restrict__ Hs) {
  const int lane = threadIdx.x & 63;
  const int ch = blockIdx.x * 4 + (threadIdx.x >> 6);   // 512 blocks x 4 waves
  const int j0 = 2 * lane, j1 = 2 * lane + 1;
  float a0 = Ac[j0 * NCH + ch], c0 = Cc[j0 * NCH + ch];
  float a1 = Ac[j1 * NCH + ch], c1 = Cc[j1 * NCH + ch];
  float a = a0 * a1;
  float c = fmaf(a1, c0, c1);
#pragma unroll
  for (int d = 1; d < 64; d <<= 1) {
    float pa = __shfl_up(a, d, 64);
    float pc = __shfl_up(c, d, 64);
    if (lane >= d) { c = fmaf(a, pc, c); a *= pa; }
  }
  float xa = __shfl_up(a, 1, 64), xc = __shfl_up(c, 1, 64);
  if (lane == 0) { xa = 1.0f; xc = 0.0f; }
  float h0 = hidden[ch];
  float hs0 = fmaf(xa, h0, xc);
  Hs[j0 * NCH + ch] = hs0;
  Hs[j1 * NCH + ch] = fmaf(a0, hs0, c0);
}

// ---- 5) replay within chunk, 2 channels/thread, fp32 out ----
__global__ void scanC_kernel(const ushort* __restrict__ z, const ushort* __restrict__ f,
                             const float* __restrict__ Hs, float* __restrict__ out) {
  int t = blockIdx.x * blockDim.x + threadIdx.x;   // 0..131071
  int ch2 = t & 1023;
  int j = t >> 10;
  float2 hv = *(const float2*)(Hs + (size_t)j * NCH + 2 * ch2);
  float h0 = hv.x, h1 = hv.y;
  const size_t base = (size_t)j * CHUNK * NCH + 2 * ch2;
  const ushort* zp = z + base;
  const ushort* fp = f + base;
  float* op = out + base;
#pragma unroll
  for (int i = 0; i < CHUNK; ++i) {
    ushort2 fv = *(const ushort2*)(fp + (size_t)i * NCH);
    ushort2 zv = *(const ushort2*)(zp + (size_t)i * NCH);
    float f0 = bf2f(fv.x), f1 = bf2f(fv.y);
    h0 = fmaf(f0, bf2f(zv.x) - h0, h0);
    h1 = fmaf(f1, bf2f(zv.y) - h1, h1);
    float2 o = {h0, h1};
    *(float2*)(op + (size_t)i * NCH) = o;
  }
  if (j == NCHUNK - 1) {
    float2 o = {h0, h1};
    *(float2*)(out + (size_t)SEQn * NCH + 2 * ch2) = o;   // h_last row
  }
}

extern "C" void kernel_launch(void* const* d_in, const int* in_sizes, int n_in,
                              void* d_out, int out_size, void* d_ws, size_t ws_size,
                              hipStream_t stream) {
  const float* X      = (const float*)d_in[0];
  const float* hidden = (const float*)d_in[1];
  const float* Wz     = (const float*)d_in[2];
  const float* bz     = (const float*)d_in[3];
  const float* Wf     = (const float*)d_in[4];
  const float* bfb    = (const float*)d_in[5];
  float* out = (float*)d_out;

  char* ws = (char*)d_ws;
  ushort* zbf = (ushort*)ws;                       // 16,777,216 B
  ushort* fbf = (ushort*)(ws + 16777216);          // 16,777,216 B
  ushort* Xbf = (ushort*)(ws + 33554432);          // 16,781,312 B (dead after gemm)
  ushort* Bm  = (ushort*)(ws + 50335744);          //    524,288 B
  // aliased over Xbf (used only after gemm completes):
  float* Ac = (float*)(ws + 33554432);
  float* Cc = (float*)(ws + 34603008);
  float* Hs = (float*)(ws + 35651584);

  pack_kernel<<<9218, 256, 0, stream>>>(X, Wz, Wf, Xbf, Bm);
  dim3 ggrid(512, 4);
  gemm_kernel<<<ggrid, 256, 0, stream>>>(Xbf, Bm, bz, bfb, zbf, fbf);
  scanA_kernel<<<512, 256, 0, stream>>>(zbf, fbf, Ac, Cc);
  scanB_kernel<<<512, 256, 0, stream>>>(hidden, Ac, Cc, Hs);
  scanC_kernel<<<512, 256, 0, stream>>>(zbf, fbf, Hs, out);
}